// Round 1
// 432.412 us; speedup vs baseline: 1.2629x; 1.2629x over previous
//
#include <hip/hip_runtime.h>
#include <hip/hip_fp16.h>

#define FDIM 128
#define SCAN_B 1024   // elements per scan block
#define NBUK 8        // node-range buckets (bucket == XCD via blockIdx&7)
#define NCHK 16       // edge chunks (= count/cursor copies to scan over)
#define MAXB 12544    // >= ceil(100000/NBUK) = 12500; 50 KB LDS

// ---------------- pass 1: LDS-histogram degree count, no global atomics -----
// Block (bucket b, chunk c): histogram chunk-c edges with row in bucket b
// into LDS, then write the plane cntC[c][lo..hi) with plain coalesced stores.
__global__ void __launch_bounds__(1024) k_cnt(const int* __restrict__ row,
                                              int* __restrict__ cntC,
                                              int nE, int n, int bspan) {
    __shared__ int hist[MAXB];
    int bucket = blockIdx.x & (NBUK - 1);
    int chunk  = blockIdx.x >> 3;
    int lo  = bucket * bspan;
    int len = min(bspan, n - lo);
    for (int j = threadIdx.x; j < len; j += 1024) hist[j] = 0;
    __syncthreads();

    int per = (((nE + NCHK - 1) / NCHK) + 3) & ~3;   // chunk size, multiple of 4
    int beg = chunk * per;
    int end = min(beg + per, nE);
    if (beg < end) {
        int nv = (end - beg) >> 2;
        const int4* row4 = reinterpret_cast<const int4*>(row + beg);
        for (int q = threadIdx.x; q < nv; q += 1024) {
            int4 r = row4[q];
            unsigned a;
            a = (unsigned)(r.x - lo); if (a < (unsigned)len) atomicAdd(&hist[a], 1);
            a = (unsigned)(r.y - lo); if (a < (unsigned)len) atomicAdd(&hist[a], 1);
            a = (unsigned)(r.z - lo); if (a < (unsigned)len) atomicAdd(&hist[a], 1);
            a = (unsigned)(r.w - lo); if (a < (unsigned)len) atomicAdd(&hist[a], 1);
        }
        for (int e = beg + (nv << 2) + threadIdx.x; e < end; e += 1024) {
            unsigned a = (unsigned)(row[e] - lo);
            if (a < (unsigned)len) atomicAdd(&hist[a], 1);
        }
    }
    __syncthreads();
    int* dst = cntC + (size_t)chunk * n + lo;
    for (int j = threadIdx.x; j < len; j += 1024) dst[j] = hist[j];
}

// ---------------- hierarchical exclusive scan, phase 1: block sums ----------
__global__ void __launch_bounds__(1024) k_scan_reduce(const int* __restrict__ cntC,
                                                      int* __restrict__ part, int n) {
    __shared__ int sd[1024];
    int i = blockIdx.x * SCAN_B + threadIdx.x;
    int v = 0;
    if (i < n) {
        v = 1;                                   // self loop
        #pragma unroll
        for (int c = 0; c < NCHK; ++c) v += cntC[(size_t)c * n + i];
    }
    sd[threadIdx.x] = v;
    __syncthreads();
    for (int off = 512; off > 0; off >>= 1) {
        if (threadIdx.x < off) sd[threadIdx.x] += sd[threadIdx.x + off];
        __syncthreads();
    }
    if (threadIdx.x == 0) part[blockIdx.x] = sd[0];
}

// ---------------- phase 2: exclusive scan of partials (1 block) -------------
__global__ void __launch_bounds__(128) k_scan_part(int* __restrict__ part,
                                                   int* __restrict__ offs,
                                                   int nb, int n) {
    __shared__ int sd[128];
    int v = (threadIdx.x < nb) ? part[threadIdx.x] : 0;
    sd[threadIdx.x] = v;
    __syncthreads();
    for (int off = 1; off < 128; off <<= 1) {
        int t = (threadIdx.x >= off) ? sd[threadIdx.x - off] : 0;
        __syncthreads();
        sd[threadIdx.x] += t;
        __syncthreads();
    }
    if (threadIdx.x < nb) part[threadIdx.x] = sd[threadIdx.x] - v;  // exclusive
    if (threadIdx.x == 127) offs[n] = sd[127];                      // total
}

// ---- phase 3: offs, dis, self-loop, and IN-PLACE absolute cursors ----------
// cntC[c][i] is rewritten to the absolute sc index where chunk c's first edge
// of node i goes: offs[i] + 1 (self loop at slot 0) + prefix of chunks < c.
__global__ void __launch_bounds__(1024) k_scan_final(int* __restrict__ cntC,
                                                     const int* __restrict__ part,
                                                     int* __restrict__ offs,
                                                     float* __restrict__ dis,
                                                     int* __restrict__ sc, int n) {
    __shared__ int sd[1024];
    int i = blockIdx.x * SCAN_B + threadIdx.x;
    int c[NCHK];
    int v = 0;
    if (i < n) {
        v = 1;
        #pragma unroll
        for (int x = 0; x < NCHK; ++x) { c[x] = cntC[(size_t)x * n + i]; v += c[x]; }
    }
    sd[threadIdx.x] = v;
    __syncthreads();
    for (int off = 1; off < 1024; off <<= 1) {
        int t = (threadIdx.x >= off) ? sd[threadIdx.x - off] : 0;
        __syncthreads();
        sd[threadIdx.x] += t;
        __syncthreads();
    }
    if (i < n) {
        int o = part[blockIdx.x] + sd[threadIdx.x] - v;    // exclusive
        offs[i] = o;
        dis[i]  = rsqrtf((float)v);                        // v >= 1 (self loop)
        sc[o]   = i;                                       // self loop at slot 0
        int b = o + 1;                                     // absolute cursor
        #pragma unroll
        for (int x = 0; x < NCHK; ++x) { cntC[(size_t)x * n + i] = b; b += c[x]; }
    }
}

// ---------------- pass 2: CSR fill via LDS cursors, no global atomics -------
// Same grid/tiling as k_cnt. Cursor plane for (chunk, bucket) is staged into
// LDS; each matching edge reserves its slot with a ds_add_rtn. Counts equal
// pass 1's, so slots are exactly [offs+1+prefix_c, ...) — order within a
// (chunk,node) group is a permutation, irrelevant for the later sum.
// bucket = blockIdx&7 == XCD id -> each bucket's sc region (1.65 MB) stays in
// one XCD's L2 and evicts as full dirty lines.
__global__ void __launch_bounds__(1024) k_fillb(const int* __restrict__ row,
                                                const int* __restrict__ col,
                                                const int* __restrict__ curC,
                                                int* __restrict__ sc,
                                                int nE, int n, int bspan) {
    __shared__ int cur[MAXB];
    int bucket = blockIdx.x & (NBUK - 1);
    int chunk  = blockIdx.x >> 3;
    int lo  = bucket * bspan;
    int len = min(bspan, n - lo);
    const int* src = curC + (size_t)chunk * n + lo;
    for (int j = threadIdx.x; j < len; j += 1024) cur[j] = src[j];
    __syncthreads();

    int per = (((nE + NCHK - 1) / NCHK) + 3) & ~3;
    int beg = chunk * per;
    int end = min(beg + per, nE);
    if (beg < end) {
        int nv = (end - beg) >> 2;
        const int4* row4 = reinterpret_cast<const int4*>(row + beg);
        const int4* col4 = reinterpret_cast<const int4*>(col + beg);
        for (int q = threadIdx.x; q < nv; q += 1024) {
            int4 r  = row4[q];
            int4 cc = col4[q];
            unsigned a;
            a = (unsigned)(r.x - lo); if (a < (unsigned)len) sc[atomicAdd(&cur[a], 1)] = cc.x;
            a = (unsigned)(r.y - lo); if (a < (unsigned)len) sc[atomicAdd(&cur[a], 1)] = cc.y;
            a = (unsigned)(r.z - lo); if (a < (unsigned)len) sc[atomicAdd(&cur[a], 1)] = cc.z;
            a = (unsigned)(r.w - lo); if (a < (unsigned)len) sc[atomicAdd(&cur[a], 1)] = cc.w;
        }
        for (int e = beg + (nv << 2) + threadIdx.x; e < end; e += 1024) {
            unsigned a = (unsigned)(row[e] - lo);
            if (a < (unsigned)len) sc[atomicAdd(&cur[a], 1)] = col[e];
        }
    }
}

// ---------------- support = dis[node] * (x @ W), stored fp16 ----------------
// Block: 256 threads = 128 features x 2 node-groups; 16 nodes per block.
__global__ void __launch_bounds__(256) k_gemm(const float* __restrict__ x,
                                              const float* __restrict__ w,
                                              const float* __restrict__ dis,
                                              __half* __restrict__ support, int n) {
    __shared__ float w_s[FDIM * FDIM];   // 64 KB
    __shared__ float x_s[16 * FDIM];     // 8 KB

    const float4* wg = reinterpret_cast<const float4*>(w);
    float4* ws4 = reinterpret_cast<float4*>(w_s);
    #pragma unroll
    for (int it = 0; it < 16; ++it)
        ws4[threadIdx.x + it * 256] = wg[threadIdx.x + it * 256];

    int nb = blockIdx.x * 16;                       // n = 100000 = 6250 * 16
    const float4* xg = reinterpret_cast<const float4*>(x + (size_t)nb * FDIM);
    float4* xs4w = reinterpret_cast<float4*>(x_s);
    #pragma unroll
    for (int it = 0; it < 2; ++it)
        xs4w[threadIdx.x + it * 256] = xg[threadIdx.x + it * 256];
    __syncthreads();

    int f  = threadIdx.x & 127;
    int ng = threadIdx.x >> 7;                      // 0..1 (8 nodes each)
    const float4* xs4 = reinterpret_cast<const float4*>(x_s);
    float acc[8] = {0, 0, 0, 0, 0, 0, 0, 0};
    for (int kg = 0; kg < 32; ++kg) {
        float w0 = w_s[(4 * kg + 0) * FDIM + f];
        float w1 = w_s[(4 * kg + 1) * FDIM + f];
        float w2 = w_s[(4 * kg + 2) * FDIM + f];
        float w3 = w_s[(4 * kg + 3) * FDIM + f];
        #pragma unroll
        for (int j = 0; j < 8; ++j) {
            float4 xv = xs4[(ng * 8 + j) * 32 + kg];   // wave-uniform -> broadcast
            acc[j] += xv.x * w0 + xv.y * w1 + xv.z * w2 + xv.w * w3;
        }
    }
    #pragma unroll
    for (int j = 0; j < 8; ++j) {
        int node = nb + ng * 8 + j;
        if (node < n)
            support[(size_t)node * FDIM + f] = __float2half(dis[node] * acc[j]);
    }
}

// ---------------- aggregation: one wave per node, half2 gathers -------------
__global__ void __launch_bounds__(64) k_agg(const __half2* __restrict__ sup2,
                                            const int* __restrict__ offs,
                                            const int* __restrict__ sc,
                                            const float* __restrict__ dis,
                                            const float* __restrict__ bias,
                                            float* __restrict__ out, int n) {
    int i  = blockIdx.x;
    int f2 = threadIdx.x;                           // 0..63 -> features 2f2,2f2+1
    int beg = offs[i], end = offs[i + 1];
    float ax = 0.f, ay = 0.f;
    int j = beg;
    for (; j + 4 <= end; j += 4) {
        int c0 = sc[j], c1 = sc[j + 1], c2 = sc[j + 2], c3 = sc[j + 3];
        float2 v0 = __half22float2(sup2[(size_t)c0 * 64 + f2]);
        float2 v1 = __half22float2(sup2[(size_t)c1 * 64 + f2]);
        float2 v2 = __half22float2(sup2[(size_t)c2 * 64 + f2]);
        float2 v3 = __half22float2(sup2[(size_t)c3 * 64 + f2]);
        ax += (v0.x + v1.x) + (v2.x + v3.x);
        ay += (v0.y + v1.y) + (v2.y + v3.y);
    }
    for (; j < end; ++j) {
        float2 v = __half22float2(sup2[(size_t)sc[j] * 64 + f2]);
        ax += v.x; ay += v.y;
    }
    float di = dis[i];
    const float2* b2 = reinterpret_cast<const float2*>(bias);
    float2 bb = b2[f2];
    float2 o;
    o.x = di * ax + bb.x;
    o.y = di * ay + bb.y;
    reinterpret_cast<float2*>(out)[(size_t)i * 64 + f2] = o;
}

extern "C" void kernel_launch(void* const* d_in, const int* in_sizes, int n_in,
                              void* d_out, int out_size, void* d_ws, size_t ws_size,
                              hipStream_t stream) {
    const float* x    = (const float*)d_in[0];
    const int*   ei   = (const int*)d_in[1];    // int32 on device (harness converts)
    const float* w    = (const float*)d_in[2];
    const float* bias = (const float*)d_in[3];
    float*       out  = (float*)d_out;

    int n  = in_sizes[0] / FDIM;   // 100000 nodes
    int nE = in_sizes[1] / 2;      // 3200000 edges
    const int* row = ei;
    const int* col = ei + nE;
    int nbscan = (n + SCAN_B - 1) / SCAN_B;          // 98 <= 128
    int bspan  = (n + NBUK - 1) / NBUK;              // 12500 <= MAXB

    // workspace carve-out (ws is re-poisoned every launch; we overwrite all)
    char* ws = (char*)d_ws;
    size_t off = 0;
    auto alloc = [&](size_t bytes) -> void* {
        void* p = ws + off;
        off += (bytes + 255) & ~(size_t)255;
        return p;
    };
    __half* support = (__half*)alloc((size_t)n * FDIM * sizeof(__half)); // 25.6 MB
    int*    cntC    = (int*)alloc((size_t)NCHK * n * sizeof(int));       //  6.4 MB (reused as cursors)
    int*    offs    = (int*)alloc((size_t)(n + 1) * sizeof(int));
    int*    part    = (int*)alloc((size_t)128 * sizeof(int));
    float*  dis     = (float*)alloc((size_t)n * sizeof(float));
    int*    sc      = (int*)alloc((size_t)(nE + n) * sizeof(int));       // 13.2 MB

    k_cnt        <<<NBUK * NCHK, 1024, 0, stream>>>(row, cntC, nE, n, bspan);
    k_scan_reduce<<<nbscan, 1024, 0, stream>>>(cntC, part, n);
    k_scan_part  <<<1, 128, 0, stream>>>(part, offs, nbscan, n);
    k_scan_final <<<nbscan, 1024, 0, stream>>>(cntC, part, offs, dis, sc, n);
    k_fillb      <<<NBUK * NCHK, 1024, 0, stream>>>(row, col, cntC, sc, nE, n, bspan);
    k_gemm       <<<(n + 15) / 16, 256, 0, stream>>>(x, w, dis, support, n);
    k_agg        <<<n, 64, 0, stream>>>((const __half2*)support, offs, sc, dis, bias, out, n);
}

// Round 2
// 351.851 us; speedup vs baseline: 1.5521x; 1.2290x over previous
//
#include <hip/hip_runtime.h>
#include <hip/hip_fp16.h>

#define FDIM 128
#define SCAN_B 1024   // elements per scan block
#define NBUK 8        // node-range buckets (bucket == XCD via blockIdx&7)
#define NCHK 16       // edge chunks (= count/cursor copies to scan over)
#define MAXB 12544    // >= ceil(100000/NBUK) = 12500; 50 KB LDS

typedef _Float16 half8 __attribute__((ext_vector_type(8)));
typedef float f32x4 __attribute__((ext_vector_type(4)));

// ---------------- pass 1: LDS-histogram degree count, no global atomics -----
__global__ void __launch_bounds__(1024) k_cnt(const int* __restrict__ row,
                                              int* __restrict__ cntC,
                                              int nE, int n, int bspan) {
    __shared__ int hist[MAXB];
    int bucket = blockIdx.x & (NBUK - 1);
    int chunk  = blockIdx.x >> 3;
    int lo  = bucket * bspan;
    int len = min(bspan, n - lo);
    for (int j = threadIdx.x; j < len; j += 1024) hist[j] = 0;
    __syncthreads();

    int per = (((nE + NCHK - 1) / NCHK) + 3) & ~3;   // chunk size, multiple of 4
    int beg = chunk * per;
    int end = min(beg + per, nE);
    if (beg < end) {
        int nv = (end - beg) >> 2;
        const int4* row4 = reinterpret_cast<const int4*>(row + beg);
        for (int q = threadIdx.x; q < nv; q += 1024) {
            int4 r = row4[q];
            unsigned a;
            a = (unsigned)(r.x - lo); if (a < (unsigned)len) atomicAdd(&hist[a], 1);
            a = (unsigned)(r.y - lo); if (a < (unsigned)len) atomicAdd(&hist[a], 1);
            a = (unsigned)(r.z - lo); if (a < (unsigned)len) atomicAdd(&hist[a], 1);
            a = (unsigned)(r.w - lo); if (a < (unsigned)len) atomicAdd(&hist[a], 1);
        }
        for (int e = beg + (nv << 2) + threadIdx.x; e < end; e += 1024) {
            unsigned a = (unsigned)(row[e] - lo);
            if (a < (unsigned)len) atomicAdd(&hist[a], 1);
        }
    }
    __syncthreads();
    int* dst = cntC + (size_t)chunk * n + lo;
    for (int j = threadIdx.x; j < len; j += 1024) dst[j] = hist[j];
}

// ---------------- hierarchical exclusive scan, phase 1: block sums ----------
__global__ void __launch_bounds__(1024) k_scan_reduce(const int* __restrict__ cntC,
                                                      int* __restrict__ part, int n) {
    __shared__ int sd[1024];
    int i = blockIdx.x * SCAN_B + threadIdx.x;
    int v = 0;
    if (i < n) {
        v = 1;                                   // self loop
        #pragma unroll
        for (int c = 0; c < NCHK; ++c) v += cntC[(size_t)c * n + i];
    }
    sd[threadIdx.x] = v;
    __syncthreads();
    for (int off = 512; off > 0; off >>= 1) {
        if (threadIdx.x < off) sd[threadIdx.x] += sd[threadIdx.x + off];
        __syncthreads();
    }
    if (threadIdx.x == 0) part[blockIdx.x] = sd[0];
}

// ---------------- phase 2: exclusive scan of partials (1 block) -------------
__global__ void __launch_bounds__(128) k_scan_part(int* __restrict__ part,
                                                   int* __restrict__ offs,
                                                   int nb, int n) {
    __shared__ int sd[128];
    int v = (threadIdx.x < nb) ? part[threadIdx.x] : 0;
    sd[threadIdx.x] = v;
    __syncthreads();
    for (int off = 1; off < 128; off <<= 1) {
        int t = (threadIdx.x >= off) ? sd[threadIdx.x - off] : 0;
        __syncthreads();
        sd[threadIdx.x] += t;
        __syncthreads();
    }
    if (threadIdx.x < nb) part[threadIdx.x] = sd[threadIdx.x] - v;  // exclusive
    if (threadIdx.x == 127) offs[n] = sd[127];                      // total
}

// ---- phase 3: offs, dis, self-loop, and IN-PLACE absolute cursors ----------
__global__ void __launch_bounds__(1024) k_scan_final(int* __restrict__ cntC,
                                                     const int* __restrict__ part,
                                                     int* __restrict__ offs,
                                                     float* __restrict__ dis,
                                                     int* __restrict__ sc, int n) {
    __shared__ int sd[1024];
    int i = blockIdx.x * SCAN_B + threadIdx.x;
    int c[NCHK];
    int v = 0;
    if (i < n) {
        v = 1;
        #pragma unroll
        for (int x = 0; x < NCHK; ++x) { c[x] = cntC[(size_t)x * n + i]; v += c[x]; }
    }
    sd[threadIdx.x] = v;
    __syncthreads();
    for (int off = 1; off < 1024; off <<= 1) {
        int t = (threadIdx.x >= off) ? sd[threadIdx.x - off] : 0;
        __syncthreads();
        sd[threadIdx.x] += t;
        __syncthreads();
    }
    if (i < n) {
        int o = part[blockIdx.x] + sd[threadIdx.x] - v;    // exclusive
        offs[i] = o;
        dis[i]  = rsqrtf((float)v);                        // v >= 1 (self loop)
        sc[o]   = i;                                       // self loop at slot 0
        int b = o + 1;                                     // absolute cursor
        #pragma unroll
        for (int x = 0; x < NCHK; ++x) { cntC[(size_t)x * n + i] = b; b += c[x]; }
    }
}

// ---------------- pass 2: CSR fill via LDS cursors, no global atomics -------
__global__ void __launch_bounds__(1024) k_fillb(const int* __restrict__ row,
                                                const int* __restrict__ col,
                                                const int* __restrict__ curC,
                                                int* __restrict__ sc,
                                                int nE, int n, int bspan) {
    __shared__ int cur[MAXB];
    int bucket = blockIdx.x & (NBUK - 1);
    int chunk  = blockIdx.x >> 3;
    int lo  = bucket * bspan;
    int len = min(bspan, n - lo);
    const int* src = curC + (size_t)chunk * n + lo;
    for (int j = threadIdx.x; j < len; j += 1024) cur[j] = src[j];
    __syncthreads();

    int per = (((nE + NCHK - 1) / NCHK) + 3) & ~3;
    int beg = chunk * per;
    int end = min(beg + per, nE);
    if (beg < end) {
        int nv = (end - beg) >> 2;
        const int4* row4 = reinterpret_cast<const int4*>(row + beg);
        const int4* col4 = reinterpret_cast<const int4*>(col + beg);
        for (int q = threadIdx.x; q < nv; q += 1024) {
            int4 r  = row4[q];
            int4 cc = col4[q];
            unsigned a;
            a = (unsigned)(r.x - lo); if (a < (unsigned)len) sc[atomicAdd(&cur[a], 1)] = cc.x;
            a = (unsigned)(r.y - lo); if (a < (unsigned)len) sc[atomicAdd(&cur[a], 1)] = cc.y;
            a = (unsigned)(r.z - lo); if (a < (unsigned)len) sc[atomicAdd(&cur[a], 1)] = cc.z;
            a = (unsigned)(r.w - lo); if (a < (unsigned)len) sc[atomicAdd(&cur[a], 1)] = cc.w;
        }
        for (int e = beg + (nv << 2) + threadIdx.x; e < end; e += 1024) {
            unsigned a = (unsigned)(row[e] - lo);
            if (a < (unsigned)len) sc[atomicAdd(&cur[a], 1)] = col[e];
        }
    }
}

// ---- W fragment precompute: hi/lo fp16 split in MFMA-native layout ---------
// Fragment fid = nt*4+ks holds W[ks*32 + (lane>>4)*8 + j][nt*16 + (lane&15)].
// hi plane at fid, lo plane (w - fp16(w) residual) at fid+32. 64 KB total,
// L2/L3-resident; every GEMM B-load is a coalesced dwordx4.
__global__ void __launch_bounds__(64) k_wprep(const float* __restrict__ w,
                                              half8* __restrict__ wfrag) {
    int fid = blockIdx.x;                 // 0..31
    int nt = fid >> 2, ks = fid & 3;
    int lane = threadIdx.x;
    int c = lane & 15, kg = lane >> 4;
    int f  = nt * 16 + c;
    int k0 = ks * 32 + kg * 8;
    half8 hi, lo;
    #pragma unroll
    for (int j = 0; j < 8; ++j) {
        float v = w[(size_t)(k0 + j) * FDIM + f];
        _Float16 h = (_Float16)v;
        hi[j] = h;
        lo[j] = (_Float16)(v - (float)h);
    }
    wfrag[fid * 64 + lane]        = hi;
    wfrag[(32 + fid) * 64 + lane] = lo;
}

// ---------------- support = dis[node] * (x @ W) via MFMA, stored fp16 -------
// 4 independent waves/block, 16 nodes each. A = x split hi/lo in-register;
// B from wfrag (L2-resident). xh*wh + xl*wh + xh*wl recovers fp32-accurate
// products (residual ~2^-22 rel), fp32 MFMA accumulation. No LDS, no barriers.
__global__ void __launch_bounds__(256) k_gemm(const float* __restrict__ x,
                                              const half8* __restrict__ wfrag,
                                              const float* __restrict__ dis,
                                              __half* __restrict__ support, int n) {
    int wave = threadIdx.x >> 6;
    int lane = threadIdx.x & 63;
    int wbase = blockIdx.x * 64 + wave * 16;
    int r  = lane & 15;                    // A row / B col / D col index
    int kg = lane >> 4;                    // k-subgroup (also D row group q)

    // ---- A fragments: node = wbase + r, k = ks*32 + kg*8 + j ----
    int noder = min(wbase + r, n - 1);     // clamp (tail block): dup reads, stores guarded
    const float* xp = x + (size_t)noder * FDIM + kg * 8;
    half8 ah[4], al[4];
    #pragma unroll
    for (int ks = 0; ks < 4; ++ks) {
        const float4* p = reinterpret_cast<const float4*>(xp + ks * 32);
        float4 f0 = p[0], f1 = p[1];
        float v[8] = {f0.x, f0.y, f0.z, f0.w, f1.x, f1.y, f1.z, f1.w};
        #pragma unroll
        for (int j = 0; j < 8; ++j) {
            _Float16 h = (_Float16)v[j];
            ah[ks][j] = h;
            al[ks][j] = (_Float16)(v[j] - (float)h);
        }
    }

    // dis for this lane's 4 output rows (same rows for every nt tile)
    float d[4];
    #pragma unroll
    for (int i = 0; i < 4; ++i)
        d[i] = dis[min(wbase + kg * 4 + i, n - 1)];

    #pragma unroll
    for (int nt = 0; nt < 8; ++nt) {
        const half8* bp = wfrag + (size_t)(nt * 4) * 64 + lane;
        f32x4 acc = {0.f, 0.f, 0.f, 0.f};
        #pragma unroll
        for (int ks = 0; ks < 4; ++ks) {
            half8 bh = bp[ks * 64];
            half8 bl = bp[32 * 64 + ks * 64];
            acc = __builtin_amdgcn_mfma_f32_16x16x32_f16(ah[ks], bh, acc, 0, 0, 0);
            acc = __builtin_amdgcn_mfma_f32_16x16x32_f16(al[ks], bh, acc, 0, 0, 0);
            acc = __builtin_amdgcn_mfma_f32_16x16x32_f16(ah[ks], bl, acc, 0, 0, 0);
        }
        // D: row = kg*4 + i (node), col = r (feature within tile)
        int f = nt * 16 + r;
        #pragma unroll
        for (int i = 0; i < 4; ++i) {
            int node = wbase + kg * 4 + i;
            if (node < n)
                support[(size_t)node * FDIM + f] = __float2half(d[i] * acc[i]);
        }
    }
}

// ---------------- aggregation: one wave per node, half2 gathers -------------
__global__ void __launch_bounds__(64) k_agg(const __half2* __restrict__ sup2,
                                            const int* __restrict__ offs,
                                            const int* __restrict__ sc,
                                            const float* __restrict__ dis,
                                            const float* __restrict__ bias,
                                            float* __restrict__ out, int n) {
    int i  = blockIdx.x;
    int f2 = threadIdx.x;                           // 0..63 -> features 2f2,2f2+1
    int beg = offs[i], end = offs[i + 1];
    float ax = 0.f, ay = 0.f;
    int j = beg;
    for (; j + 4 <= end; j += 4) {
        int c0 = sc[j], c1 = sc[j + 1], c2 = sc[j + 2], c3 = sc[j + 3];
        float2 v0 = __half22float2(sup2[(size_t)c0 * 64 + f2]);
        float2 v1 = __half22float2(sup2[(size_t)c1 * 64 + f2]);
        float2 v2 = __half22float2(sup2[(size_t)c2 * 64 + f2]);
        float2 v3 = __half22float2(sup2[(size_t)c3 * 64 + f2]);
        ax += (v0.x + v1.x) + (v2.x + v3.x);
        ay += (v0.y + v1.y) + (v2.y + v3.y);
    }
    for (; j < end; ++j) {
        float2 v = __half22float2(sup2[(size_t)sc[j] * 64 + f2]);
        ax += v.x; ay += v.y;
    }
    float di = dis[i];
    const float2* b2 = reinterpret_cast<const float2*>(bias);
    float2 bb = b2[f2];
    float2 o;
    o.x = di * ax + bb.x;
    o.y = di * ay + bb.y;
    reinterpret_cast<float2*>(out)[(size_t)i * 64 + f2] = o;
}

extern "C" void kernel_launch(void* const* d_in, const int* in_sizes, int n_in,
                              void* d_out, int out_size, void* d_ws, size_t ws_size,
                              hipStream_t stream) {
    const float* x    = (const float*)d_in[0];
    const int*   ei   = (const int*)d_in[1];    // int32 on device (harness converts)
    const float* w    = (const float*)d_in[2];
    const float* bias = (const float*)d_in[3];
    float*       out  = (float*)d_out;

    int n  = in_sizes[0] / FDIM;   // 100000 nodes
    int nE = in_sizes[1] / 2;      // 3200000 edges
    const int* row = ei;
    const int* col = ei + nE;
    int nbscan = (n + SCAN_B - 1) / SCAN_B;          // 98 <= 128
    int bspan  = (n + NBUK - 1) / NBUK;              // 12500 <= MAXB

    // workspace carve-out (ws is re-poisoned every launch; we overwrite all)
    char* ws = (char*)d_ws;
    size_t off = 0;
    auto alloc = [&](size_t bytes) -> void* {
        void* p = ws + off;
        off += (bytes + 255) & ~(size_t)255;
        return p;
    };
    __half* support = (__half*)alloc((size_t)n * FDIM * sizeof(__half)); // 25.6 MB
    int*    cntC    = (int*)alloc((size_t)NCHK * n * sizeof(int));       //  6.4 MB (reused as cursors)
    int*    offs    = (int*)alloc((size_t)(n + 1) * sizeof(int));
    int*    part    = (int*)alloc((size_t)128 * sizeof(int));
    float*  dis     = (float*)alloc((size_t)n * sizeof(float));
    int*    sc      = (int*)alloc((size_t)(nE + n) * sizeof(int));       // 13.2 MB
    half8*  wfrag   = (half8*)alloc((size_t)64 * 64 * sizeof(half8));    // 64 KB

    k_wprep      <<<32, 64, 0, stream>>>(w, wfrag);
    k_cnt        <<<NBUK * NCHK, 1024, 0, stream>>>(row, cntC, nE, n, bspan);
    k_scan_reduce<<<nbscan, 1024, 0, stream>>>(cntC, part, n);
    k_scan_part  <<<1, 128, 0, stream>>>(part, offs, nbscan, n);
    k_scan_final <<<nbscan, 1024, 0, stream>>>(cntC, part, offs, dis, sc, n);
    k_fillb      <<<NBUK * NCHK, 1024, 0, stream>>>(row, col, cntC, sc, nE, n, bspan);
    k_gemm       <<<(n + 63) / 64, 256, 0, stream>>>(x, wfrag, dis, support, n);
    k_agg        <<<n, 64, 0, stream>>>((const __half2*)support, offs, sc, dis, bias, out, n);
}